// Round 13
// baseline (70.780 us; speedup 1.0000x reference)
//
#include <hip/hip_runtime.h>
#include <hip/hip_bf16.h>
#include <cstddef>
#include <cstdint>

#define BB    8
#define TT    2048
#define KIN   1024
#define NOUT  512
#define CHUNK 32
#define NCHUNK (TT / CHUNK)   // 64

#define BM 64
#define BN 128
#define BK 64
#define NKSTEP (KIN / BK)     // 16
#define NPAGE  (KIN / 32)     // 32 8KB pages per 128-row strip
#define TILEB 8192            // one 128x32 f16 page = 8KB

typedef __attribute__((ext_vector_type(4))) float          f32x4;
typedef __attribute__((ext_vector_type(4))) unsigned int   u32x4;
typedef _Float16 f16x8 __attribute__((ext_vector_type(8)));

// ---------------------------------------------------------------------------
// f32 [R][1024] -> f16 tiled+preswizzled pages (verified R10/R11): page
// (r>>7, k>>5) is 8KB contiguous, inner [row][slot^((row>>1)&3)]*16B == the
// 0-conflict LDS image, so the GEMM stages it LINEARLY via G2L.
// ---------------------------------------------------------------------------
__global__ __launch_bounds__(256) void conv_tiled_f16(
    const float* __restrict__ src, unsigned char* __restrict__ dst, int total) {
  int idx = blockIdx.x * blockDim.x + threadIdx.x;
  const int stride = gridDim.x * blockDim.x;
  for (; idx < total; idx += stride) {
    const int r  = idx >> 7;        // global row
    const int s8 = idx & 127;       // 8-element k-slot (16B f16)
    const float* p = src + (size_t)r * KIN + s8 * 8;
    float4 a = *reinterpret_cast<const float4*>(p);
    float4 b = *reinterpret_cast<const float4*>(p + 4);
    f16x8 h;
    h[0] = (_Float16)a.x; h[1] = (_Float16)a.y;
    h[2] = (_Float16)a.z; h[3] = (_Float16)a.w;
    h[4] = (_Float16)b.x; h[5] = (_Float16)b.y;
    h[6] = (_Float16)b.z; h[7] = (_Float16)b.w;
    const int row  = r & 127;
    const int page = (r >> 7) * NPAGE + (s8 >> 2);
    const int slot = (s8 & 3) ^ ((row >> 1) & 3);
    *reinterpret_cast<f16x8*>(dst + (size_t)page * TILEB + row * 64 + slot * 16) = h;
  }
}

#define G2L(gp, sp)                                                        \
  __builtin_amdgcn_global_load_lds(                                       \
      (const __attribute__((address_space(1))) void*)(gp),                \
      (__attribute__((address_space(3))) void*)(sp), 16, 0, 0)

// ---------------------------------------------------------------------------
// fp16 MFMA GEMM — occupancy-fixed m97 structure: 64x128 tile, BK=64,
// 4 waves (32x64 each), 24KB LDS (A 8KB | B 16KB), 16 K-steps, 2-barrier
// drain loop, 6 linear G2L/step from contiguous pre-swizzled pages,
// 16 MFMA/wave-step.  grid (256 m, 4 n) = 1024 blocks = 4 RESIDENT BLOCKS/CU
// (m114: implicit cross-block overlap hides the vmcnt drain — the measured
// mechanism R5-R12's 2-block/CU structure lacked).
// A rows = 64-row halves of the 128-row pages (offset half*4096; swizzle key
// (r64>>1)&3 consistent because 64 % 4 == 0).
// C stored f16 to workspace; epilogue fuses vend scan (1 chunk per wave).
// 256 % 8 == 0 -> an m-strip's 4 n-blocks share an XCD (verified R3+).
// ---------------------------------------------------------------------------
__global__ __launch_bounds__(256, 4) void gemm_f16(
    const unsigned char* __restrict__ Xt, const unsigned char* __restrict__ Wt,
    const float* __restrict__ bias, const float* __restrict__ decay,
    unsigned short* __restrict__ Cws, float* __restrict__ vend) {
  __shared__ __align__(16) unsigned char smem[8192 + 16384];  // A 8KB | B 16KB

  const int tid  = threadIdx.x;
  const int wave = tid >> 6;
  const int lane = tid & 63;
  const int m0 = blockIdx.x * BM;
  const int n0 = blockIdx.y * BN;
  const int wm = (wave >> 1) * 32;   // 2x2 waves: 32x64 output each
  const int wn = (wave & 1) * 64;
  const int frow = lane & 15;
  const int g    = lane >> 4;

  unsigned char* sA = smem;
  unsigned char* sB = smem + 8192;

  // A: 64-row half of the 128-row strip's pages
  const int strip = m0 >> 7;
  const int half  = (m0 >> 6) & 1;
  const unsigned char* srcA =
      Xt + (size_t)strip * NPAGE * TILEB + half * 4096 + tid * 16;
  const unsigned char* srcB = Wt + (size_t)(n0 >> 7) * NPAGE * TILEB + tid * 16;
  const int ldsw = wave * 1024;

  // fragment-read swizzled k-slot offset (R8/R10/R11-verified ~0 conflicts)
  const int swzr = (g ^ ((frow >> 1) & 3)) << 4;

  f32x4 acc[2][4] = {};

  for (int t = 0; t < NKSTEP; ++t) {
    __syncthreads();                       // prev compute done
    const size_t poff = (size_t)(2 * t) * TILEB;   // two pages per K-step
    // A: 4KB half of page 2t and of page 2t+1
    G2L(srcA + poff,         sA + ldsw);
    G2L(srcA + poff + TILEB, sA + 4096 + ldsw);
    // B: two full contiguous 8KB pages
#pragma unroll
    for (int q = 0; q < 4; ++q)
      G2L(srcB + poff + q * 4096, sB + q * 4096 + ldsw);
    __syncthreads();                       // vmcnt drained -> tiles ready

#pragma unroll
    for (int kk = 0; kk < 2; ++kk) {
      f16x8 af[2];
#pragma unroll
      for (int mi = 0; mi < 2; ++mi)
        af[mi] = *reinterpret_cast<const f16x8*>(
            sA + kk * 4096 + (wm + mi * 16 + frow) * 64 + swzr);
#pragma unroll
      for (int ni = 0; ni < 4; ++ni) {
        f16x8 bf = *reinterpret_cast<const f16x8*>(
            sB + kk * 8192 + (wn + ni * 16 + frow) * 64 + swzr);
#pragma unroll
        for (int mi = 0; mi < 2; ++mi)
          acc[mi][ni] = __builtin_amdgcn_mfma_f32_16x16x32_f16(af[mi], bf, acc[mi][ni], 0, 0, 0);
      }
    }
  }

  // --- epilogue: bias + f16 C store to workspace (verified R11/R12) ---
  const int colb = n0 + wn + frow;
  const int rowb = m0 + wm + (g << 2);
  float bv[4];
#pragma unroll
  for (int ni = 0; ni < 4; ++ni) bv[ni] = bias[colb + ni * 16];
#pragma unroll
  for (int mi = 0; mi < 2; ++mi) {
#pragma unroll
    for (int r = 0; r < 4; ++r) {
#pragma unroll
      for (int ni = 0; ni < 4; ++ni) {
        const _Float16 hv = (_Float16)(acc[mi][ni][r] + bv[ni]);
        Cws[(size_t)(rowb + mi * 16 + r) * NOUT + colb + ni * 16] =
            __builtin_bit_cast(unsigned short, hv);
      }
    }
  }

  // --- fused vend: each wave's 32 rows = ONE chunk; Horner + shfl ---
  // row-in-chunk = mi*16 + g*4 + r; weight d^(31-row); per-lane partial
  // s_mi = omd*Horner4; u = d^(12-4g) * (s0*d16 + s1); shfl_xor(16,32) sums g.
  {
    float rr[4];
#pragma unroll
    for (int ni = 0; ni < 4; ++ni) {
      const float d  = decay[colb + ni * 16];
      const float bb = bv[ni];
      const float omd = 1.0f - d;
      const float dd = d * d, d4 = dd * dd, d8 = d4 * d4;
      const float d16 = d8 * d8, d12 = d8 * d4;
      const float dpg = (g == 0) ? d12 : (g == 1) ? d8 : (g == 2) ? d4 : 1.0f;
      float s[2];
#pragma unroll
      for (int mi = 0; mi < 2; ++mi) {
        float v = acc[mi][ni][0] + bb;
        v = v * d + (acc[mi][ni][1] + bb);
        v = v * d + (acc[mi][ni][2] + bb);
        v = v * d + (acc[mi][ni][3] + bb);
        s[mi] = omd * v;
      }
      float u = dpg * (s[0] * d16 + s[1]);
      u += __shfl_xor(u, 16); u += __shfl_xor(u, 32);
      rr[ni] = u;
    }
    const int b     = m0 >> 11;
    const int chunk = ((m0 & (TT - 1)) >> 5) + (wm >> 5);
    const float val = (g == 0) ? rr[0] : (g == 1) ? rr[1] : (g == 2) ? rr[2] : rr[3];
    const int col   = n0 + wn + frow + g * 16;
    vend[((size_t)b * NCHUNK + chunk) * NOUT + col] = val;
  }
}

// ---------------------------------------------------------------------------
// Fallback f32 GEMM (verified R1) — only if workspace is too small.
// ---------------------------------------------------------------------------
__global__ __launch_bounds__(256) void gemm_f32_64x64(
    const float* __restrict__ X, const float* __restrict__ W,
    const float* __restrict__ bias, float* __restrict__ C) {
  __shared__ float As[16][65];
  __shared__ float Bs[16][65];
  const int m0  = blockIdx.y * 64;
  const int n0  = blockIdx.x * 64;
  const int tid = threadIdx.x;
  const int tx  = tid & 15;
  const int ty  = tid >> 4;
  const int lr  = tid >> 2;
  const int lk  = (tid & 3) << 2;
  float acc[4][4] = {};
  const float* xa = X + (size_t)(m0 + lr) * KIN + lk;
  const float* wb = W + (size_t)(n0 + lr) * KIN + lk;
  for (int k0 = 0; k0 < KIN; k0 += 16) {
    float4 av = *reinterpret_cast<const float4*>(xa + k0);
    float4 bv = *reinterpret_cast<const float4*>(wb + k0);
    As[lk + 0][lr] = av.x; As[lk + 1][lr] = av.y;
    As[lk + 2][lr] = av.z; As[lk + 3][lr] = av.w;
    Bs[lk + 0][lr] = bv.x; Bs[lk + 1][lr] = bv.y;
    Bs[lk + 2][lr] = bv.z; Bs[lk + 3][lr] = bv.w;
    __syncthreads();
#pragma unroll
    for (int k = 0; k < 16; ++k) {
      float a[4], b[4];
#pragma unroll
      for (int i = 0; i < 4; ++i) a[i] = As[k][ty * 4 + i];
#pragma unroll
      for (int j = 0; j < 4; ++j) b[j] = Bs[k][tx * 4 + j];
#pragma unroll
      for (int i = 0; i < 4; ++i)
#pragma unroll
        for (int j = 0; j < 4; ++j) acc[i][j] += a[i] * b[j];
    }
    __syncthreads();
  }
  const int n = n0 + tx * 4;
  float4 bv = *reinterpret_cast<const float4*>(&bias[n]);
#pragma unroll
  for (int i = 0; i < 4; ++i) {
    const int m = m0 + ty * 4 + i;
    float4 r;
    r.x = acc[i][0] + bv.x; r.y = acc[i][1] + bv.y;
    r.z = acc[i][2] + bv.z; r.w = acc[i][3] + bv.w;
    *reinterpret_cast<float4*>(&C[(size_t)m * NOUT + n]) = r;
  }
}

// ---------------------------------------------------------------------------
// Fixup with integrated chunk-carry compose (verified R11/R12): block (b,c)
// composes vinit from vend, scans its chunk from f16 Cws, writes out+states.
// ---------------------------------------------------------------------------
__global__ __launch_bounds__(512) void scan_fixup2(
    const unsigned short* __restrict__ Cws, const float* __restrict__ vend,
    const float* __restrict__ decay, float* __restrict__ out,
    float* __restrict__ states) {
  const int b = blockIdx.x / NCHUNK;
  const int c = blockIdx.x % NCHUNK;
  const int o = threadIdx.x;
  const float d   = decay[o];
  const float omd = 1.0f - d;
  const float dd = d * d, d4 = dd * dd, d8 = d4 * d4, d16 = d8 * d8;
  const float dL = d16 * d16;   // d^CHUNK

  float v = 0.0f;
  const float* vp = vend + (size_t)b * NCHUNK * NOUT + o;
  for (int cc = 0; cc < c; ++cc) v = dL * v + vp[(size_t)cc * NOUT];

  size_t obase = ((size_t)b * TT + (size_t)c * CHUNK) * NOUT + o;
  size_t sbase = ((size_t)b * (TT + 1) + (size_t)c * CHUNK + 1) * NOUT + o;
#pragma unroll 4
  for (int k = 0; k < CHUNK; ++k) {
    const unsigned short hu = Cws[obase + (size_t)k * NOUT];
    const float cur = (float)__builtin_bit_cast(_Float16, hu);
    v = d * v + omd * cur;
    out[obase + (size_t)k * NOUT]    = v;
    states[sbase + (size_t)k * NOUT] = v;
  }
  if (c == 0) states[((size_t)b * (TT + 1)) * NOUT + o] = 0.0f;
}

__global__ __launch_bounds__(512) void scan_seq(
    float* __restrict__ C, float* __restrict__ states,
    const float* __restrict__ decay) {
  const int b = blockIdx.x;
  const int o = threadIdx.x;
  const float d   = decay[o];
  const float omd = 1.0f - d;
  float v = 0.0f;
  states[((size_t)b * (TT + 1)) * NOUT + o] = 0.0f;
  for (int t = 0; t < TT; ++t) {
    const size_t oi = ((size_t)b * TT + t) * NOUT + o;
    float x = C[oi];
    v = d * v + omd * x;
    C[oi] = v;
    states[((size_t)b * (TT + 1) + t + 1) * NOUT + o] = v;
  }
}

extern "C" void kernel_launch(void* const* d_in, const int* in_sizes, int n_in,
                              void* d_out, int out_size, void* d_ws, size_t ws_size,
                              hipStream_t stream) {
  const float* x     = (const float*)d_in[0];  // [B,T,IN]
  const float* w     = (const float*)d_in[1];  // [OUT,IN]
  const float* bias  = (const float*)d_in[2];  // [OUT]
  const float* decay = (const float*)d_in[3];  // [OUT]

  float* out    = (float*)d_out;                 // [B,T,OUT]
  float* states = out + (size_t)BB * TT * NOUT;  // [1,B,T+1,OUT]

  const size_t szXb = (size_t)BB * TT * KIN * sizeof(_Float16);     // 32 MB
  const size_t szWb = (size_t)NOUT * KIN * sizeof(_Float16);        // 1 MB
  const size_t szCb = (size_t)BB * TT * NOUT * sizeof(_Float16);    // 16.8 MB
  const size_t scan_elems = (size_t)BB * NCHUNK * NOUT;
  const size_t need = szXb + szWb + szCb + scan_elems * sizeof(float);  // ~52 MB

  if (ws_size >= need) {
    unsigned char*  Xt   = (unsigned char*)d_ws;
    unsigned char*  Wt   = Xt + szXb;
    unsigned short* Cws  = (unsigned short*)(Wt + szWb);
    float*          vend = (float*)(Cws + (size_t)BB * TT * NOUT);

    conv_tiled_f16<<<2048, 256, 0, stream>>>(x, Xt, BB * TT * (KIN / 8));
    conv_tiled_f16<<<256,  256, 0, stream>>>(w, Wt, NOUT * (KIN / 8));
    gemm_f16<<<dim3((BB * TT) / BM, NOUT / BN), 256, 0, stream>>>(
        Xt, Wt, bias, decay, Cws, vend);
    scan_fixup2<<<BB * NCHUNK, NOUT, 0, stream>>>(Cws, vend, decay, out, states);
  } else {
    gemm_f32_64x64<<<dim3(NOUT / 64, (BB * TT) / 64), 256, 0, stream>>>(x, w, bias, out);
    scan_seq<<<BB, NOUT, 0, stream>>>(out, states, decay);
  }
}